// Round 9
// baseline (1656.293 us; speedup 1.0000x reference)
//
#include <hip/hip_runtime.h>
#include <hip/hip_bf16.h>
#include <stdint.h>

#define DEV static __device__ __forceinline__

constexpr int N_ = 50000;
constexpr int E_ = 1600000;
constexpr int G_ = 256;

typedef __attribute__((ext_vector_type(8))) short short8;
typedef __attribute__((ext_vector_type(4))) float float4v;

DEV uint16_t f2bf(float f){
  uint32_t u = __float_as_uint(f);
  uint32_t r = (u + 0x7fffu + ((u >> 16) & 1u)) >> 16;
  return (uint16_t)r;
}
DEV float bf2f(uint16_t v){ return __uint_as_float((uint32_t)v << 16); }
DEV void unpack2(uint32_t p, float& a, float& b){
  a = __uint_as_float(p << 16);
  b = __uint_as_float(p & 0xffff0000u);
}
DEV uint32_t pack2(float a, float b){
  return (uint32_t)f2bf(a) | ((uint32_t)f2bf(b) << 16);
}
DEV short8 lds_load8(const uint16_t* p){
  union { short8 v; uint2 u[2]; } c;
  c.u[0] = *(const uint2*)p;
  c.u[1] = *(const uint2*)(p + 4);
  return c.v;
}

// ---------------- x column stats ----------------
__global__ __launch_bounds__(256) void k_xstats(const float* __restrict__ x, float* __restrict__ xstats){
  __shared__ float lst[96];
  int t = threadIdx.x;
  if (t < 96) lst[t] = 0.f;
  __syncthreads();
  int gid = blockIdx.x * 256 + t;
  int c4 = (gid % 12) * 4;
  float s[4] = {0,0,0,0}, q[4] = {0,0,0,0};
  const float4v* x4 = (const float4v*)x;
  for (int i = gid; i < N_ * 12; i += 64512){
    float4v v = x4[i];
    #pragma unroll
    for (int j = 0; j < 4; j++){ s[j] += v[j]; q[j] += v[j]*v[j]; }
  }
  #pragma unroll
  for (int j = 0; j < 4; j++){
    atomicAdd(&lst[c4 + j], s[j]);
    atomicAdd(&lst[48 + c4 + j], q[j]);
  }
  __syncthreads();
  if (t < 96) atomicAdd(&xstats[t], lst[t]);
}

__global__ void k_xfin(const float* __restrict__ xstats, const float* __restrict__ g,
                       const float* __restrict__ b, float* __restrict__ sx, float* __restrict__ tx){
  int c = threadIdx.x;
  if (c < 48){
    float m = xstats[c] / (float)N_;
    float v = xstats[48 + c] / (float)N_ - m*m;
    float s = g[c] / sqrtf(v + 1e-5f);
    sx[c] = s; tx[c] = b[c] - m*s;
  }
}

// ---------------- histogram of col ----------------
__global__ __launch_bounds__(256) void k_hist(const int* __restrict__ ei, int* __restrict__ counts){
  int e = blockIdx.x * 256 + threadIdx.x;
  if (e < E_) atomicAdd(&counts[ei[E_ + e]], 1);
}

// ---------------- 1/count ----------------
__global__ __launch_bounds__(256) void k_invc(const int* __restrict__ counts, float* __restrict__ invc){
  int n = blockIdx.x * 256 + threadIdx.x;
  if (n < N_){ int c = counts[n]; invc[n] = (c > 0) ? 1.f/(float)c : 0.f; }
}

// ---------------- two-level scan ----------------
__global__ __launch_bounds__(256) void k_scanA(const int* __restrict__ counts, int* __restrict__ bsum){
  __shared__ int ws[4];
  int b = blockIdx.x, t = threadIdx.x, lane = t & 63, w = t >> 6;
  int i0 = b*1024 + t*4;
  int s = 0;
  #pragma unroll
  for (int j = 0; j < 4; j++){ int i = i0 + j; if (i < N_) s += counts[i]; }
  for (int d = 1; d < 64; d <<= 1) s += __shfl_xor(s, d);
  if (lane == 0) ws[w] = s;
  __syncthreads();
  if (t == 0) bsum[b] = ws[0] + ws[1] + ws[2] + ws[3];
}
__global__ void k_scanB(const int* __restrict__ bsum, int* __restrict__ boff, int* __restrict__ off, int nb){
  int t = threadIdx.x;
  int v = (t < nb) ? bsum[t] : 0;
  int x = v;
  for (int d = 1; d < 64; d <<= 1){ int y = __shfl_up(x, d); if (t >= d) x += y; }
  if (t < nb) boff[t] = x - v;
  if (t == 63) off[N_] = x;
}
__global__ __launch_bounds__(256) void k_scanC(const int* __restrict__ counts, const int* __restrict__ boff,
                                               int* __restrict__ off, int* __restrict__ cur){
  __shared__ int ws[4];
  int b = blockIdx.x, t = threadIdx.x, lane = t & 63, w = t >> 6;
  int i0 = b*1024 + t*4;
  int v0 = (i0+0 < N_) ? counts[i0+0] : 0;
  int v1 = (i0+1 < N_) ? counts[i0+1] : 0;
  int v2 = (i0+2 < N_) ? counts[i0+2] : 0;
  int v3 = (i0+3 < N_) ? counts[i0+3] : 0;
  int ts = v0+v1+v2+v3, xs = ts;
  for (int d = 1; d < 64; d <<= 1){ int y = __shfl_up(xs, d); if (lane >= d) xs += y; }
  if (lane == 63) ws[w] = xs;
  __syncthreads();
  int woff = 0;
  for (int k = 0; k < w; k++) woff += ws[k];
  int excl = xs - ts + woff + boff[b];
  int e0 = excl, e1 = e0+v0, e2 = e1+v1, e3 = e2+v2;
  if (i0+0 < N_){ off[i0+0] = e0; cur[i0+0] = e0; }
  if (i0+1 < N_){ off[i0+1] = e1; cur[i0+1] = e1; }
  if (i0+2 < N_){ off[i0+2] = e2; cur[i0+2] = e2; }
  if (i0+3 < N_){ off[i0+3] = e3; cur[i0+3] = e3; }
}

// ---------------- counting-sort placement ----------------
__global__ __launch_bounds__(256) void k_place(const int* __restrict__ ei, int* __restrict__ cur,
                                               int2* __restrict__ rcs){
  int e = blockIdx.x * 256 + threadIdx.x;
  if (e < E_){
    int c = ei[E_ + e];
    int p = atomicAdd(&cur[c], 1);
    rcs[p] = make_int2(ei[e], c);
  }
}

// ---------------- weight precomputation ----------------
// Mt[n][k]=M^T; W1t[n][k]=eW1_top^T (K pad 64); N1t[n][j]=n1W1_top^T (pad 64)
__global__ __launch_bounds__(256) void k_wprep(
    const float* __restrict__ eW1, const float* __restrict__ eW2, const float* __restrict__ n1W1,
    const float* __restrict__ n1W2, const float* __restrict__ n2W1,
    const float* __restrict__ n2W2, const float* __restrict__ glW1,
    const float* __restrict__ n1b2, const float* __restrict__ n2b2,
    uint16_t* __restrict__ Mt, float* __restrict__ Wcomb,
    float* __restrict__ M3, float* __restrict__ c1, float* __restrict__ c3,
    uint16_t* __restrict__ W1t, uint16_t* __restrict__ N1t){
  int flat = blockIdx.x * 256 + threadIdx.x;
  if (flat < 16384){
    int n = flat & 127, k = flat >> 7;
    float a = 0.f;
    for (int j = 0; j < 128; j++) a += eW2[k*128 + j] * n1W1[(48 + j)*128 + n];
    Mt[n*128 + k] = f2bf(a);
  } else if (flat < 32768){
    int b = flat - 16384;
    int n = b & 127, j = b >> 7;
    float a = 0.f;
    for (int m = 0; m < 128; m++) a += n1W2[j*128 + m] * n2W1[(48 + m)*128 + n];
    Wcomb[(48 + j)*128 + n] = a;
  } else if (flat < 38912){
    int b = flat - 32768;
    int n = b & 127, k = b >> 7;
    Wcomb[k*128 + n] = n2W1[k*128 + n];
  } else if (flat < 55296){
    int b = flat - 38912;
    int n = b & 127, j = b >> 7;
    float a = 0.f;
    for (int m = 0; m < 128; m++) a += n2W2[j*128 + m] * glW1[m*128 + n];
    M3[j*128 + n] = a;
  } else if (flat < 55552){
    int e = flat - 55296;
    if (e < 128){
      float a = 0.f;
      for (int m = 0; m < 128; m++) a += n1b2[m] * n2W1[(48 + m)*128 + e];
      c1[e] = a;
    } else {
      int n = e - 128;
      float a = 0.f;
      for (int m = 0; m < 128; m++) a += n2b2[m] * glW1[m*128 + n];
      c3[n] = a;
    }
  } else if (flat < 63744){
    int b = flat - 55552;
    int n = b & 127, k = b >> 7;
    W1t[n*64 + k] = (k < 48) ? f2bf(eW1[k*128 + n]) : (uint16_t)0;
  } else if (flat < 71936){
    int b = flat - 63744;
    int n = b & 127, j = b >> 7;
    N1t[n*64 + j] = (j < 48) ? f2bf(n1W1[j*128 + n]) : (uint16_t)0;
  }
}

// ---------------- node prep: Bn = xn@eW1_bot (bf16) + xn (bf16) ----------------
__global__ __launch_bounds__(256) void k_nodegemm(
    const float* __restrict__ x, const float* __restrict__ sx, const float* __restrict__ tx,
    const float* __restrict__ eW1,
    uint16_t* __restrict__ Bn, uint16_t* __restrict__ xn){
  __shared__ float xT[48][36];
  __shared__ float W[48][128];
  int t = threadIdx.x;
  int n0 = blockIdx.x * 32;
  for (int idx = t; idx < 384; idx += 256){
    int r = idx / 12, q = idx % 12;
    int n = n0 + r;
    float4v v = {0.f,0.f,0.f,0.f};
    if (n < N_) v = *(const float4v*)&x[(size_t)n*48 + q*4];
    float xv[4];
    #pragma unroll
    for (int i = 0; i < 4; i++){
      int k = q*4 + i;
      xv[i] = v[i] * sx[k] + tx[k];
      xT[k][r] = xv[i];
    }
    if (n < N_){
      uint2 pv;
      pv.x = pack2(xv[0], xv[1]);
      pv.y = pack2(xv[2], xv[3]);
      *(uint2*)&xn[(size_t)n*48 + q*4] = pv;
    }
  }
  {
    const float4v* src4 = (const float4v*)(eW1 + 48*128);
    float4v* W4 = (float4v*)W;
    for (int idx = t; idx < 1536; idx += 256) W4[idx] = src4[idx];
  }
  __syncthreads();
  int cg = t & 31, ng = t >> 5;
  float acc[4][4] = {{0.f}};
  #pragma unroll 4
  for (int k = 0; k < 48; k++){
    float4v xv = *(const float4v*)&xT[k][ng*4];
    float4v wv = *(const float4v*)&W[k][cg*4];
    #pragma unroll
    for (int i = 0; i < 4; i++)
      #pragma unroll
      for (int j = 0; j < 4; j++)
        acc[i][j] += xv[i]*wv[j];
  }
  #pragma unroll
  for (int i = 0; i < 4; i++){
    int n = n0 + ng*4 + i;
    if (n >= N_) continue;
    uint2 pv;
    pv.x = pack2(acc[i][0], acc[i][1]);
    pv.y = pack2(acc[i][2], acc[i][3]);
    *(uint2*)&Bn[(size_t)n*128 + cg*4] = pv;
  }
}

// ---------------- generic BN finalize ----------------
__global__ void k_bnfin(const float* __restrict__ statsR, int reps, const float* __restrict__ g,
                        const float* __restrict__ be, float* __restrict__ s_out, float* __restrict__ t_out,
                        float inv_n){
  int c = threadIdx.x;
  if (c >= 128) return;
  float sm = 0.f, sq = 0.f;
  for (int r = 0; r < reps; r++){ sm += statsR[r*256 + c]; sq += statsR[r*256 + 128 + c]; }
  float m = sm * inv_n;
  float v = sq * inv_n - m*m;
  float s = g[c] / sqrtf(v + 1e-5f);
  s_out[c] = s;
  t_out[c] = be[c] - m*s;
}

// ======== E-scale kernels v3: gather 96B xn[row] instead of 512B A/C rows.
// 128 edges/block, 512 threads, 8 waves; ~79-80 KB LDS -> 2 blocks/CU (16 waves).
// h1e = xnr@W1t^T + B[col] (Bseg staged from sorted cols); h1n = [relu_e|xnr]@[Mt;N1t]^T.

// ---------------- estats2: BN stats of h1e ----------------
__global__ __launch_bounds__(512, 4) void k_estats2(
    const int2* __restrict__ rcs, const uint16_t* __restrict__ xn,
    const uint16_t* __restrict__ Bn, const uint16_t* __restrict__ W1t,
    float* __restrict__ estR){
  __shared__ __align__(16) uint16_t XNR[128*68];
  __shared__ __align__(16) uint16_t Hh[128*132];
  __shared__ __align__(16) uint16_t Wb[128*68];
  __shared__ __align__(16) uint16_t Bseg[32*128];
  __shared__ float lst[256];
  __shared__ int ssid[128], scol[128], scseg[32];
  __shared__ int sm_w0, snseg;
  const int t = threadIdx.x;
  const long i0 = (long)blockIdx.x * 128;
  const int lane = t & 63, w = t >> 6;
  const int m = lane & 15, quad = lane >> 4;
  uint32_t* XNRd = (uint32_t*)XNR;
  uint32_t* Wd = (uint32_t*)Wb;
  uint32_t* Hd = (uint32_t*)Hh;

  if (t < 256) lst[t] = 0.f;

  int sid_loc = 0; bool bnd = false; int myc = 0;
  if (t < 128){
    myc = rcs[i0 + t].y;
    int prevc = (t > 0) ? rcs[i0 + t - 1].y : myc;
    bnd = (t > 0) && (myc != prevc);
    unsigned long long mask = __ballot(bnd);
    sid_loc = __popcll(mask << (63 - lane));
    scol[t] = myc;
    if (t == 63) sm_w0 = sid_loc;
  }
  {
    int e = t >> 2, q = t & 3;
    int r = rcs[i0 + e].x;
    const uint2* src = (const uint2*)(xn + (size_t)r*48 + q*12);
    uint2 d0 = src[0], d1 = src[1], d2 = src[2];
    uint32_t* dst = XNRd + e*34 + q*6;
    *(uint2*)dst = d0; *(uint2*)(dst+2) = d1; *(uint2*)(dst+4) = d2;
  }
  for (int idx = t; idx < 1024; idx += 512){
    int rr = idx >> 3;
    XNRd[rr*34 + 24 + (idx & 7)] = 0;
  }
  {
    const uint32_t* src = (const uint32_t*)W1t;
    for (int idx = t; idx < 4096; idx += 512){
      int n = idx >> 5, d = idx & 31;
      Wd[n*34 + d] = src[n*32 + d];
    }
  }
  __syncthreads();
  if (t >= 64 && t < 128) sid_loc += sm_w0;
  if (t < 128){
    ssid[t] = sid_loc;
    if ((bnd || t == 0) && sid_loc < 32) scseg[sid_loc] = myc;
    if (t == 127) snseg = sid_loc + 1;
  }
  __syncthreads();
  {
    int ns = snseg; if (ns > 32) ns = 32;
    uint32_t* Bsegd = (uint32_t*)Bseg;
    const uint32_t* Bnd = (const uint32_t*)Bn;
    for (int idx = t; idx < ns*64; idx += 512){
      int s = idx >> 6, d = idx & 63;
      Bsegd[s*64 + d] = Bnd[(size_t)scseg[s]*64 + d];
    }
  }
  __syncthreads();

  float4v acc[8];
  #pragma unroll
  for (int nt = 0; nt < 8; nt++){ acc[nt][0]=0.f; acc[nt][1]=0.f; acc[nt][2]=0.f; acc[nt][3]=0.f; }
  {
    const uint16_t* aptr = XNR + (w*16 + m)*68 + quad*8;
    const uint16_t* bbase = Wb + m*68 + quad*8;
    #pragma unroll
    for (int ks = 0; ks < 2; ks++){
      short8 af = lds_load8(aptr + ks*32);
      #pragma unroll
      for (int nt = 0; nt < 8; nt++){
        short8 bf = lds_load8(bbase + nt*16*68 + ks*32);
        acc[nt] = __builtin_amdgcn_mfma_f32_16x16x32_bf16(af, bf, acc[nt], 0, 0, 0);
      }
    }
  }
  // h1e = acc + B -> Hh
  {
    int elb = w*16 + quad*4;
    int sids[4];
    #pragma unroll
    for (int reg = 0; reg < 4; reg++) sids[reg] = ssid[elb + reg];
    #pragma unroll
    for (int nt = 0; nt < 8; nt++){
      int col = nt*16 + m;
      #pragma unroll
      for (int reg = 0; reg < 4; reg++){
        float b = (sids[reg] < 32) ? bf2f(Bseg[sids[reg]*128 + col])
                                   : bf2f(Bn[(size_t)scol[elb+reg]*128 + col]);
        Hh[(elb+reg)*132 + col] = f2bf(acc[nt][reg] + b);
      }
    }
  }
  __syncthreads();
  {
    int cp = t & 63, eg = t >> 6;
    float ss0=0,qq0=0,ss1=0,qq1=0;
    #pragma unroll
    for (int it = 0; it < 16; it++){
      int e = it*8 + eg;
      uint32_t ph = Hd[e*66 + cp];
      float h0,h1; unpack2(ph,h0,h1);
      ss0 += h0; qq0 += h0*h0; ss1 += h1; qq1 += h1*h1;
    }
    atomicAdd(&lst[2*cp], ss0);
    atomicAdd(&lst[2*cp+1], ss1);
    atomicAdd(&lst[128+2*cp], qq0);
    atomicAdd(&lst[128+2*cp+1], qq1);
  }
  __syncthreads();
  if (t < 256) atomicAdd(&estR[(blockIdx.x & 63)*256 + t], lst[t]);
}

// ---------------- epass0 v3: h1n stats ----------------
__global__ __launch_bounds__(512, 4) void k_epass0(
    const int2* __restrict__ rcs, const uint16_t* __restrict__ xn,
    const uint16_t* __restrict__ Bn, const uint16_t* __restrict__ W1t,
    const uint16_t* __restrict__ Mt, const uint16_t* __restrict__ N1t,
    const float* __restrict__ se, const float* __restrict__ te,
    float* __restrict__ n1R){
  __shared__ __align__(16) uint16_t XNR[128*68];
  __shared__ __align__(16) uint16_t Hh[128*132];
  __shared__ __align__(16) uint16_t Wb[128*68];
  __shared__ __align__(16) uint16_t Bseg[32*128];
  __shared__ float sete[256];
  __shared__ float lst[256];
  __shared__ int ssid[128], scol[128], scseg[32];
  __shared__ int sm_w0, snseg;
  const int t = threadIdx.x;
  const long i0 = (long)blockIdx.x * 128;
  const int lane = t & 63, w = t >> 6;
  const int m = lane & 15, quad = lane >> 4;
  uint32_t* XNRd = (uint32_t*)XNR;
  uint32_t* Wd = (uint32_t*)Wb;
  uint32_t* Hd = (uint32_t*)Hh;

  if (t < 256) lst[t] = 0.f;
  if (t < 128){ sete[t] = se[t]; sete[128 + t] = te[t]; }

  int sid_loc = 0; bool bnd = false; int myc = 0;
  if (t < 128){
    myc = rcs[i0 + t].y;
    int prevc = (t > 0) ? rcs[i0 + t - 1].y : myc;
    bnd = (t > 0) && (myc != prevc);
    unsigned long long mask = __ballot(bnd);
    sid_loc = __popcll(mask << (63 - lane));
    scol[t] = myc;
    if (t == 63) sm_w0 = sid_loc;
  }
  {
    int e = t >> 2, q = t & 3;
    int r = rcs[i0 + e].x;
    const uint2* src = (const uint2*)(xn + (size_t)r*48 + q*12);
    uint2 d0 = src[0], d1 = src[1], d2 = src[2];
    uint32_t* dst = XNRd + e*34 + q*6;
    *(uint2*)dst = d0; *(uint2*)(dst+2) = d1; *(uint2*)(dst+4) = d2;
  }
  for (int idx = t; idx < 1024; idx += 512){
    int rr = idx >> 3;
    XNRd[rr*34 + 24 + (idx & 7)] = 0;
  }
  {
    const uint32_t* src = (const uint32_t*)W1t;
    for (int idx = t; idx < 4096; idx += 512){
      int n = idx >> 5, d = idx & 31;
      Wd[n*34 + d] = src[n*32 + d];
    }
  }
  __syncthreads();
  if (t >= 64 && t < 128) sid_loc += sm_w0;
  if (t < 128){
    ssid[t] = sid_loc;
    if ((bnd || t == 0) && sid_loc < 32) scseg[sid_loc] = myc;
    if (t == 127) snseg = sid_loc + 1;
  }
  __syncthreads();
  {
    int ns = snseg; if (ns > 32) ns = 32;
    uint32_t* Bsegd = (uint32_t*)Bseg;
    const uint32_t* Bnd = (const uint32_t*)Bn;
    for (int idx = t; idx < ns*64; idx += 512){
      int s = idx >> 6, d = idx & 63;
      Bsegd[s*64 + d] = Bnd[(size_t)scseg[s]*64 + d];
    }
  }
  __syncthreads();

  // MFMA1: Za = xnr @ W1
  float4v acc[8];
  #pragma unroll
  for (int nt = 0; nt < 8; nt++){ acc[nt][0]=0.f; acc[nt][1]=0.f; acc[nt][2]=0.f; acc[nt][3]=0.f; }
  {
    const uint16_t* aptr = XNR + (w*16 + m)*68 + quad*8;
    const uint16_t* bbase = Wb + m*68 + quad*8;
    #pragma unroll
    for (int ks = 0; ks < 2; ks++){
      short8 af = lds_load8(aptr + ks*32);
      #pragma unroll
      for (int nt = 0; nt < 8; nt++){
        short8 bf = lds_load8(bbase + nt*16*68 + ks*32);
        acc[nt] = __builtin_amdgcn_mfma_f32_16x16x32_bf16(af, bf, acc[nt], 0, 0, 0);
      }
    }
  }
  // relu_e = relu((Za+B)*se+te) -> Hh
  {
    int elb = w*16 + quad*4;
    int sids[4];
    #pragma unroll
    for (int reg = 0; reg < 4; reg++) sids[reg] = ssid[elb + reg];
    #pragma unroll
    for (int nt = 0; nt < 8; nt++){
      int col = nt*16 + m;
      float sc = sete[col], tc = sete[128 + col];
      #pragma unroll
      for (int reg = 0; reg < 4; reg++){
        float b = (sids[reg] < 32) ? bf2f(Bseg[sids[reg]*128 + col])
                                   : bf2f(Bn[(size_t)scol[elb+reg]*128 + col]);
        float v = fmaxf(0.f, (acc[nt][reg] + b)*sc + tc);
        Hh[(elb+reg)*132 + col] = f2bf(v);
      }
    }
  }

  // MFMA2: h1n = [relu_e | xnr] @ [Mt; N1t], 3 staged K-chunks of 64
  float4v acc2[8];
  #pragma unroll
  for (int nt = 0; nt < 8; nt++){ acc2[nt][0]=0.f; acc2[nt][1]=0.f; acc2[nt][2]=0.f; acc2[nt][3]=0.f; }
  const uint32_t* Mtd = (const uint32_t*)Mt;
  const uint32_t* N1td = (const uint32_t*)N1t;
  for (int s = 0; s < 3; s++){
    __syncthreads();
    for (int idx = t; idx < 4096; idx += 512){
      int n = idx >> 5, d = idx & 31;
      Wd[n*34 + d] = (s < 2) ? Mtd[n*64 + s*32 + d] : N1td[n*32 + d];
    }
    __syncthreads();
    const uint16_t* a2 = (s == 2) ? (XNR + (w*16 + m)*68 + quad*8)
                                  : (Hh + (w*16 + m)*132 + s*64 + quad*8);
    const uint16_t* bbase = Wb + m*68 + quad*8;
    #pragma unroll
    for (int ks = 0; ks < 2; ks++){
      short8 af = lds_load8(a2 + ks*32);
      #pragma unroll
      for (int nt = 0; nt < 8; nt++){
        short8 bf = lds_load8(bbase + nt*16*68 + ks*32);
        acc2[nt] = __builtin_amdgcn_mfma_f32_16x16x32_bf16(af, bf, acc2[nt], 0, 0, 0);
      }
    }
  }
  __syncthreads();
  // h1n -> Hh
  {
    int elb = w*16 + quad*4;
    #pragma unroll
    for (int nt = 0; nt < 8; nt++)
      #pragma unroll
      for (int reg = 0; reg < 4; reg++)
        Hh[(elb+reg)*132 + nt*16 + m] = f2bf(acc2[nt][reg]);
  }
  __syncthreads();
  {
    int cp = t & 63, eg = t >> 6;
    float ss0=0,qq0=0,ss1=0,qq1=0;
    #pragma unroll
    for (int it = 0; it < 16; it++){
      int e = it*8 + eg;
      uint32_t ph = Hd[e*66 + cp];
      float h0,h1; unpack2(ph,h0,h1);
      ss0 += h0; qq0 += h0*h0; ss1 += h1; qq1 += h1*h1;
    }
    atomicAdd(&lst[2*cp], ss0);
    atomicAdd(&lst[2*cp+1], ss1);
    atomicAdd(&lst[128+2*cp], qq0);
    atomicAdd(&lst[128+2*cp+1], qq1);
  }
  __syncthreads();
  if (t < 256) atomicAdd(&n1R[(blockIdx.x & 63)*256 + t], lst[t]);
}

// ---------------- epass1 v3: recompute h1n, BN+relu, segment-aggregate ----------------
__global__ __launch_bounds__(512, 4) void k_epass1(
    const int2* __restrict__ rcs, const uint16_t* __restrict__ xn,
    const uint16_t* __restrict__ Bn, const uint16_t* __restrict__ W1t,
    const uint16_t* __restrict__ Mt, const uint16_t* __restrict__ N1t,
    const float* __restrict__ se, const float* __restrict__ te,
    const float* __restrict__ sn1, const float* __restrict__ tn1,
    float* __restrict__ aggf){
  __shared__ __align__(16) uint16_t XNR[128*68];
  __shared__ __align__(16) uint16_t Hh[128*132];
  __shared__ __align__(16) uint16_t Wb[128*68];   // weights -> segacc (32*128 floats)
  __shared__ __align__(16) uint16_t Bseg[32*128];
  __shared__ float sete[256];                     // se|te -> sn1|tn1
  __shared__ int ssid[128], scol[128], scseg[32];
  __shared__ int sm_w0, snseg;
  const int t = threadIdx.x;
  const long i0 = (long)blockIdx.x * 128;
  const int lane = t & 63, w = t >> 6;
  const int m = lane & 15, quad = lane >> 4;
  uint32_t* XNRd = (uint32_t*)XNR;
  uint32_t* Wd = (uint32_t*)Wb;
  uint32_t* Hd = (uint32_t*)Hh;
  float* segacc = (float*)Wb;

  if (t < 128){ sete[t] = se[t]; sete[128 + t] = te[t]; }

  int sid_loc = 0; bool bnd = false; int myc = 0;
  if (t < 128){
    myc = rcs[i0 + t].y;
    int prevc = (t > 0) ? rcs[i0 + t - 1].y : myc;
    bnd = (t > 0) && (myc != prevc);
    unsigned long long mask = __ballot(bnd);
    sid_loc = __popcll(mask << (63 - lane));
    scol[t] = myc;
    if (t == 63) sm_w0 = sid_loc;
  }
  {
    int e = t >> 2, q = t & 3;
    int r = rcs[i0 + e].x;
    const uint2* src = (const uint2*)(xn + (size_t)r*48 + q*12);
    uint2 d0 = src[0], d1 = src[1], d2 = src[2];
    uint32_t* dst = XNRd + e*34 + q*6;
    *(uint2*)dst = d0; *(uint2*)(dst+2) = d1; *(uint2*)(dst+4) = d2;
  }
  for (int idx = t; idx < 1024; idx += 512){
    int rr = idx >> 3;
    XNRd[rr*34 + 24 + (idx & 7)] = 0;
  }
  {
    const uint32_t* src = (const uint32_t*)W1t;
    for (int idx = t; idx < 4096; idx += 512){
      int n = idx >> 5, d = idx & 31;
      Wd[n*34 + d] = src[n*32 + d];
    }
  }
  __syncthreads();
  if (t >= 64 && t < 128) sid_loc += sm_w0;
  if (t < 128){
    ssid[t] = sid_loc;
    if ((bnd || t == 0) && sid_loc < 32) scseg[sid_loc] = myc;
    if (t == 127) snseg = sid_loc + 1;
  }
  __syncthreads();
  {
    int ns = snseg; if (ns > 32) ns = 32;
    uint32_t* Bsegd = (uint32_t*)Bseg;
    const uint32_t* Bnd = (const uint32_t*)Bn;
    for (int idx = t; idx < ns*64; idx += 512){
      int s = idx >> 6, d = idx & 63;
      Bsegd[s*64 + d] = Bnd[(size_t)scseg[s]*64 + d];
    }
  }
  __syncthreads();

  // MFMA1
  float4v acc[8];
  #pragma unroll
  for (int nt = 0; nt < 8; nt++){ acc[nt][0]=0.f; acc[nt][1]=0.f; acc[nt][2]=0.f; acc[nt][3]=0.f; }
  {
    const uint16_t* aptr = XNR + (w*16 + m)*68 + quad*8;
    const uint16_t* bbase = Wb + m*68 + quad*8;
    #pragma unroll
    for (int ks = 0; ks < 2; ks++){
      short8 af = lds_load8(aptr + ks*32);
      #pragma unroll
      for (int nt = 0; nt < 8; nt++){
        short8 bf = lds_load8(bbase + nt*16*68 + ks*32);
        acc[nt] = __builtin_amdgcn_mfma_f32_16x16x32_bf16(af, bf, acc[nt], 0, 0, 0);
      }
    }
  }
  // relu_e -> Hh
  {
    int elb = w*16 + quad*4;
    int sids[4];
    #pragma unroll
    for (int reg = 0; reg < 4; reg++) sids[reg] = ssid[elb + reg];
    #pragma unroll
    for (int nt = 0; nt < 8; nt++){
      int col = nt*16 + m;
      float sc = sete[col], tc = sete[128 + col];
      #pragma unroll
      for (int reg = 0; reg < 4; reg++){
        float b = (sids[reg] < 32) ? bf2f(Bseg[sids[reg]*128 + col])
                                   : bf2f(Bn[(size_t)scol[elb+reg]*128 + col]);
        float v = fmaxf(0.f, (acc[nt][reg] + b)*sc + tc);
        Hh[(elb+reg)*132 + col] = f2bf(v);
      }
    }
  }

  // MFMA2
  float4v acc2[8];
  #pragma unroll
  for (int nt = 0; nt < 8; nt++){ acc2[nt][0]=0.f; acc2[nt][1]=0.f; acc2[nt][2]=0.f; acc2[nt][3]=0.f; }
  const uint32_t* Mtd = (const uint32_t*)Mt;
  const uint32_t* N1td = (const uint32_t*)N1t;
  for (int s = 0; s < 3; s++){
    __syncthreads();
    for (int idx = t; idx < 4096; idx += 512){
      int n = idx >> 5, d = idx & 31;
      Wd[n*34 + d] = (s < 2) ? Mtd[n*64 + s*32 + d] : N1td[n*32 + d];
    }
    __syncthreads();
    const uint16_t* a2 = (s == 2) ? (XNR + (w*16 + m)*68 + quad*8)
                                  : (Hh + (w*16 + m)*132 + s*64 + quad*8);
    const uint16_t* bbase = Wb + m*68 + quad*8;
    #pragma unroll
    for (int ks = 0; ks < 2; ks++){
      short8 af = lds_load8(a2 + ks*32);
      #pragma unroll
      for (int nt = 0; nt < 8; nt++){
        short8 bf = lds_load8(bbase + nt*16*68 + ks*32);
        acc2[nt] = __builtin_amdgcn_mfma_f32_16x16x32_bf16(af, bf, acc2[nt], 0, 0, 0);
      }
    }
  }
  __syncthreads();
  // h1n -> Hh; sete <- sn1|tn1; zero segacc (Wb dead)
  {
    int elb = w*16 + quad*4;
    #pragma unroll
    for (int nt = 0; nt < 8; nt++)
      #pragma unroll
      for (int reg = 0; reg < 4; reg++)
        Hh[(elb+reg)*132 + nt*16 + m] = f2bf(acc2[nt][reg]);
  }
  if (t < 128){ sete[t] = sn1[t]; sete[128 + t] = tn1[t]; }
  for (int idx = t; idx < 32*128; idx += 512) segacc[idx] = 0.f;
  __syncthreads();

  // P4: BN+relu, segment walk (8 groups x 16 consecutive edges)
  {
    int cp = t & 63, eg = t >> 6;
    float s0 = sete[2*cp], s1 = sete[2*cp+1];
    float b0 = sete[128+2*cp], b1 = sete[128+2*cp+1];
    int nseg = snseg;
    bool lp = (nseg <= 32);
    int cursid = ssid[eg*16];
    int curcol = scol[eg*16];
    float r0 = 0.f, r1 = 0.f;
    for (int it = 0; it < 16; it++){
      int e = eg*16 + it;
      uint32_t ph = Hd[e*66 + cp];
      float h0,h1; unpack2(ph,h0,h1);
      float v0 = fmaxf(0.f, h0*s0 + b0);
      float v1 = fmaxf(0.f, h1*s1 + b1);
      int sid = ssid[e];
      if (sid != cursid){
        if (lp){ atomicAdd(&segacc[cursid*128 + 2*cp], r0); atomicAdd(&segacc[cursid*128 + 2*cp+1], r1); }
        else { atomicAdd(&aggf[(size_t)curcol*128 + 2*cp], r0); atomicAdd(&aggf[(size_t)curcol*128 + 2*cp+1], r1); }
        cursid = sid; curcol = scol[e]; r0 = 0.f; r1 = 0.f;
      }
      r0 += v0; r1 += v1;
    }
    if (lp){ atomicAdd(&segacc[cursid*128 + 2*cp], r0); atomicAdd(&segacc[cursid*128 + 2*cp+1], r1); }
    else { atomicAdd(&aggf[(size_t)curcol*128 + 2*cp], r0); atomicAdd(&aggf[(size_t)curcol*128 + 2*cp+1], r1); }
    __syncthreads();
    if (lp){
      for (int idx = t; idx < nseg*64; idx += 512){
        int s = idx >> 6, cpp = idx & 63;
        float v0 = segacc[s*128 + 2*cpp], v1 = segacc[s*128 + 2*cpp+1];
        int c = scseg[s];
        float* dst = &aggf[(size_t)c*128 + 2*cpp];
        if (s == 0 || s == nseg - 1){ atomicAdd(dst, v0); atomicAdd(dst+1, v1); }
        else { dst[0] = v0; dst[1] = v1; }
      }
    }
  }
}

// ---------------- n2 GEMM ----------------
__global__ __launch_bounds__(256) void k_n2(const float* __restrict__ x,
    const float* __restrict__ sx, const float* __restrict__ tx,
    const float* __restrict__ aggf, const float* __restrict__ invc,
    const float* __restrict__ Wc, const float* __restrict__ c1, const int* __restrict__ counts,
    float* __restrict__ hn2, float* __restrict__ n2R){
  __shared__ float xT[44][36];
  __shared__ float wT[44][128];
  __shared__ float lst[256];
  int t = threadIdx.x;
  int n0 = blockIdx.x * 32;
  int cg = t & 31, ng = t >> 5;
  lst[t] = 0.f;
  float acc[4][4] = {{0.f}};
  for (int kc = 0; kc < 176; kc += 44){
    __syncthreads();
    for (int idx = t; idx < 32*44; idx += 256){
      int r = idx / 44, k = idx % 44;
      int n = n0 + r, kk = kc + k;
      float v = 0.f;
      if (n < N_){
        if (kk < 48) v = x[(size_t)n*48 + kk] * sx[kk] + tx[kk];
        else         v = aggf[(size_t)n*128 + (kk - 48)] * invc[n];
      }
      xT[k][r] = v;
    }
    for (int idx = t; idx < 44*128; idx += 256){
      int k = idx >> 7, c = idx & 127;
      wT[k][c] = Wc[(kc + k)*128 + c];
    }
    __syncthreads();
    for (int k = 0; k < 44; k++){
      float4v xv = *(const float4v*)&xT[k][ng*4];
      float4v wv = *(const float4v*)&wT[k][cg*4];
      #pragma unroll
      for (int i = 0; i < 4; i++)
        #pragma unroll
        for (int j = 0; j < 4; j++)
          acc[i][j] += xv[i]*wv[j];
    }
  }
  float csum[4] = {0,0,0,0}, cqs[4] = {0,0,0,0};
  for (int i = 0; i < 4; i++){
    int n = n0 + ng*4 + i;
    if (n >= N_) continue;
    bool ok = counts[n] > 0;
    float4v o;
    #pragma unroll
    for (int j = 0; j < 4; j++){
      float vv = acc[i][j] + (ok ? c1[cg*4 + j] : 0.f);
      o[j] = vv; csum[j] += vv; cqs[j] += vv*vv;
    }
    *(float4v*)&hn2[(size_t)n*128 + cg*4] = o;
  }
  #pragma unroll
  for (int j = 0; j < 4; j++){
    atomicAdd(&lst[cg*4 + j], csum[j]);
    atomicAdd(&lst[128 + cg*4 + j], cqs[j]);
  }
  __syncthreads();
  atomicAdd(&n2R[(blockIdx.x & 63)*256 + t], lst[t]);
}

// ---------------- graph offsets from sorted batch ----------------
__global__ void k_goff(const int* __restrict__ batch, int* __restrict__ goff){
  int g = threadIdx.x;
  int lo = 0, hi = N_;
  while (lo < hi){ int mid = (lo + hi) >> 1; if (batch[mid] < g) lo = mid + 1; else hi = mid; }
  goff[g] = lo;
  if (g == 0) goff[256] = N_;
}

// ---------------- per-graph mean of relu(bn(h_n2)) ----------------
__global__ __launch_bounds__(128) void k_gmean(const float* __restrict__ hn2, const int* __restrict__ goff,
    const float* __restrict__ sn2, const float* __restrict__ tn2, float* __restrict__ gmean){
  int g = blockIdx.x, c = threadIdx.x;
  int b = goff[g], e = goff[g+1];
  float s = sn2[c], tt = tn2[c], a = 0.f;
  for (int r = b; r < e; r++) a += fmaxf(0.f, hn2[(size_t)r*128 + c]*s + tt);
  gmean[g*128 + c] = (e > b) ? a/(float)(e - b) : 0.f;
}

// ---------------- hg = gmean@M3 + cond*c3, gl stats ----------------
__global__ __launch_bounds__(256) void k_hg(const float* __restrict__ gmean, const float* __restrict__ M3,
    const float* __restrict__ c3, const int* __restrict__ goff,
    float* __restrict__ hg, float* __restrict__ gls){
  int idx = blockIdx.x * 256 + threadIdx.x;
  int g = idx >> 7, c = idx & 127;
  float a = 0.f;
  for (int k = 0; k < 128; k++) a += gmean[g*128 + k] * M3[k*128 + c];
  if (goff[g+1] > goff[g]) a += c3[c];
  hg[idx] = a;
  atomicAdd(&gls[c], a);
  atomicAdd(&gls[128 + c], a*a);
}

// ---------------- final output ----------------
__global__ __launch_bounds__(256) void k_out(const float* __restrict__ hg, const float* __restrict__ sgl,
    const float* __restrict__ tgl, const float* __restrict__ glW2, const float* __restrict__ glb2,
    float* __restrict__ out){
  int idx = blockIdx.x * 256 + threadIdx.x;
  int g = idx >> 1, o = idx & 1;
  float a = 0.f;
  for (int c = 0; c < 128; c++){
    float r = fmaxf(0.f, hg[g*128 + c]*sgl[c] + tgl[c]);
    a += r * glW2[c*2 + o];
  }
  out[idx] = a + glb2[o];
}

extern "C" void kernel_launch(void* const* d_in, const int* in_sizes, int n_in,
                              void* d_out, int out_size, void* d_ws, size_t ws_size,
                              hipStream_t stream){
  const float* x     = (const float*)d_in[0];
  const int*   ei    = (const int*)d_in[1];
  const int*   batch = (const int*)d_in[2];
  const float* bn_g  = (const float*)d_in[3];
  const float* bn_b  = (const float*)d_in[4];
  const float* eW1   = (const float*)d_in[5];
  const float* e_g   = (const float*)d_in[7];
  const float* e_be  = (const float*)d_in[8];
  const float* eW2   = (const float*)d_in[9];
  const float* n1W1  = (const float*)d_in[11];
  const float* n1_g  = (const float*)d_in[13];
  const float* n1_be = (const float*)d_in[14];
  const float* n1W2  = (const float*)d_in[15];
  const float* n1b2  = (const float*)d_in[16];
  const float* n2W1  = (const float*)d_in[17];
  const float* n2_g  = (const float*)d_in[19];
  const float* n2_be = (const float*)d_in[20];
  const float* n2W2  = (const float*)d_in[21];
  const float* n2b2  = (const float*)d_in[22];
  const float* glW1  = (const float*)d_in[23];
  const float* gl_g  = (const float*)d_in[25];
  const float* gl_be = (const float*)d_in[26];
  const float* glW2  = (const float*)d_in[27];
  const float* glb2  = (const float*)d_in[28];
  float* out = (float*)d_out;

  char* w = (char*)d_ws;
  size_t off = 0;
  auto take = [&](size_t bytes) -> char* {
    char* p = w + off;
    off = (off + bytes + 511) & ~(size_t)511;
    return p;
  };

  const size_t ZONE_WORDS = 96 + 3*64*256 + 256 + N_;
  float* zone   = (float*)take(ZONE_WORDS * 4);
  float* xstats = zone;
  float* estR   = zone + 96;
  float* n1R    = zone + 96 + 64*256;
  float* n2R    = zone + 96 + 2*64*256;
  float* gls    = zone + 96 + 3*64*256;
  int*   counts = (int*)(zone + 96 + 3*64*256 + 256);

  float* sx = (float*)take(48*4);   float* tx = (float*)take(48*4);
  float* se = (float*)take(128*4);  float* te = (float*)take(128*4);
  float* sn1 = (float*)take(128*4); float* tn1 = (float*)take(128*4);
  float* sn2 = (float*)take(128*4); float* tn2 = (float*)take(128*4);
  float* sgl = (float*)take(128*4); float* tgl = (float*)take(128*4);
  float* c1 = (float*)take(128*4);  float* c3 = (float*)take(128*4);
  float* invc  = (float*)take((size_t)N_*4);
  float* Wcomb = (float*)take(176*128*4);
  float* M3    = (float*)take(128*128*4);
  float* gmean = (float*)take(G_*128*4);
  float* hg    = (float*)take(G_*128*4);
  int* offs = (int*)take((N_+1)*4);
  int* cur  = (int*)take(N_*4);
  int* goff = (int*)take(257*4);
  int* bsum = (int*)take(64*4);
  int* boff = (int*)take(64*4);
  uint16_t* Mt  = (uint16_t*)take(128*128*2);
  uint16_t* W1t = (uint16_t*)take(128*64*2);
  uint16_t* N1t = (uint16_t*)take(128*64*2);
  uint16_t* xn  = (uint16_t*)take((size_t)N_*48*2);
  uint16_t* Bn  = (uint16_t*)take((size_t)N_*128*2);
  float* aggf  = (float*)take((size_t)N_*128*4);
  float* hn2   = (float*)take((size_t)N_*128*4);
  int2* rcs = (int2*)take((size_t)E_*8);

  if (off > ws_size) return;   // clean fail, no fault

  hipMemsetAsync(zone, 0, ZONE_WORDS*4, stream);
  hipMemsetAsync(aggf, 0, (size_t)N_*128*4, stream);

  const int NB = (N_ + 1023) / 1024;  // 49
  hipLaunchKernelGGL(k_xstats, dim3(252), dim3(256), 0, stream, x, xstats);
  hipLaunchKernelGGL(k_hist, dim3((E_+255)/256), dim3(256), 0, stream, ei, counts);
  hipLaunchKernelGGL(k_xfin, dim3(1), dim3(64), 0, stream, xstats, bn_g, bn_b, sx, tx);
  hipLaunchKernelGGL(k_scanA, dim3(NB), dim3(256), 0, stream, counts, bsum);
  hipLaunchKernelGGL(k_scanB, dim3(1), dim3(64), 0, stream, bsum, boff, offs, NB);
  hipLaunchKernelGGL(k_scanC, dim3(NB), dim3(256), 0, stream, counts, boff, offs, cur);
  hipLaunchKernelGGL(k_place, dim3((E_+255)/256), dim3(256), 0, stream, ei, cur, rcs);
  hipLaunchKernelGGL(k_invc, dim3((N_+255)/256), dim3(256), 0, stream, counts, invc);
  hipLaunchKernelGGL(k_wprep, dim3(281), dim3(256), 0, stream,
                     eW1, eW2, n1W1, n1W2, n2W1, n2W2, glW1, n1b2, n2b2,
                     Mt, Wcomb, M3, c1, c3, W1t, N1t);
  hipLaunchKernelGGL(k_nodegemm, dim3((N_+31)/32), dim3(256), 0, stream,
                     x, sx, tx, eW1, Bn, xn);
  hipLaunchKernelGGL(k_estats2, dim3(E_/128), dim3(512), 0, stream,
                     rcs, xn, Bn, W1t, estR);
  hipLaunchKernelGGL(k_bnfin, dim3(1), dim3(128), 0, stream, estR, 64, e_g, e_be, se, te, 1.f/(float)E_);
  hipLaunchKernelGGL(k_epass0, dim3(E_/128), dim3(512), 0, stream,
                     rcs, xn, Bn, W1t, Mt, N1t, se, te, n1R);
  hipLaunchKernelGGL(k_bnfin, dim3(1), dim3(128), 0, stream, n1R, 64, n1_g, n1_be, sn1, tn1, 1.f/(float)E_);
  hipLaunchKernelGGL(k_epass1, dim3(E_/128), dim3(512), 0, stream,
                     rcs, xn, Bn, W1t, Mt, N1t, se, te, sn1, tn1, aggf);
  hipLaunchKernelGGL(k_n2, dim3((N_+31)/32), dim3(256), 0, stream,
                     x, sx, tx, aggf, invc, Wcomb, c1, counts, hn2, n2R);
  hipLaunchKernelGGL(k_bnfin, dim3(1), dim3(128), 0, stream, n2R, 64, n2_g, n2_be, sn2, tn2, 1.f/(float)N_);
  hipLaunchKernelGGL(k_goff, dim3(1), dim3(256), 0, stream, batch, goff);
  hipLaunchKernelGGL(k_gmean, dim3(256), dim3(128), 0, stream, hn2, goff, sn2, tn2, gmean);
  hipLaunchKernelGGL(k_hg, dim3(128), dim3(256), 0, stream, gmean, M3, c3, goff, hg, gls);
  hipLaunchKernelGGL(k_bnfin, dim3(1), dim3(128), 0, stream, gls, 1, gl_g, gl_be, sgl, tgl, 1.f/(float)G_);
  hipLaunchKernelGGL(k_out, dim3(2), dim3(256), 0, stream, hg, sgl, tgl, glW2, glb2, out);
}